// Round 1
// 396.621 us; speedup vs baseline: 1.0193x; 1.0193x over previous
//
#include <hip/hip_runtime.h>
#include <hip/hip_bf16.h>
#include <math.h>

// GLA block, MI355X. Round 12: all four big GEMMs ported to the 8-phase
// 256-wide counted-vmcnt schedule (T2 swizzle + T3/T4 counted waits + T5
// setprio). BM=256, BN template {256 (qvg) / 128 (Wo,FFN1,FFN2)}, BK=64,
// 512 threads (8 waves 2Mx4N), 4 quadrant-phases/K-tile, vmcnt(4|3) at tile
// boundaries only (never 0 in steady state). LDS: dynamic 128/96 KB,
// XOR-swizzled (slot ^= row&7) via pre-swizzled global source + swizzled
// ds_read (rule 21). GLA + LN + transposes unchanged. 12 dispatches.

using bf16 = __hip_bfloat16;
typedef __attribute__((ext_vector_type(8))) short bf16x8;
typedef __attribute__((ext_vector_type(4))) float f32x4;

#define BT 4096
#define HM 1024
#define DK 32
#define DV 64
#define NC 32
#define CHK 64

#if defined(__has_builtin)
#if __has_builtin(__builtin_amdgcn_global_load_lds)
#define HAVE_GLDS 1
#endif
#endif

#ifdef HAVE_GLDS
#define GLDS16(g, l) __builtin_amdgcn_global_load_lds( \
    (const __attribute__((address_space(1))) unsigned int*)(g), \
    (__attribute__((address_space(3))) unsigned int*)(l), 16, 0, 0)
#else
#define GLDS16(g, l) (*(int4*)(l) = *(const int4*)(g))
#endif

__device__ __forceinline__ float b2f(bf16 v) { return __bfloat162float(v); }
__device__ __forceinline__ bf16 f2b(float v) { return __float2bfloat16(v); }
__device__ __forceinline__ float clampf(float v, float lim) {
    return fminf(fmaxf(v, -lim), lim);
}
__device__ __forceinline__ float lo16(unsigned int u) {
    union { unsigned int i; float f; } c; c.i = u << 16; return c.f;
}
__device__ __forceinline__ float hi16(unsigned int u) {
    union { unsigned int i; float f; } c; c.i = u & 0xffff0000u; return c.f;
}
__device__ __forceinline__ void acc8(float a, uint4 r, float* o) {
    o[0] += a * lo16(r.x); o[1] += a * hi16(r.x);
    o[2] += a * lo16(r.y); o[3] += a * hi16(r.y);
    o[4] += a * lo16(r.z); o[5] += a * hi16(r.z);
    o[6] += a * lo16(r.w); o[7] += a * hi16(r.w);
}

// ---------------- dtype detector ----------------
__global__ __launch_bounds__(256) void detect_dtype(
    const unsigned int* __restrict__ x, int* __restrict__ flag)
{
    int tid = threadIdx.x;
    int cnt = 0;
    for (int i = 0; i < 16; ++i) {
        unsigned int w = x[tid * 16 + i];
        unsigned int e_lo = (w >> 7) & 0xffu;
        unsigned int e_hi = (w >> 23) & 0xffu;
        cnt += (e_lo >= 110 && e_lo <= 135 && e_hi >= 110 && e_hi <= 135) ? 1 : 0;
    }
    __shared__ int red[256];
    red[tid] = cnt;
    __syncthreads();
    for (int s = 128; s > 0; s >>= 1) {
        if (tid < s) red[tid] += red[tid + s];
        __syncthreads();
    }
    if (tid == 0) *flag = (red[0] > 2048) ? 1 : 0;  // 1 = bf16 buffers, 0 = f32
}

// ---------------- fused small-tensor cvt ----------
struct SmallCvt { const void* s[8]; bf16* d[8]; int n[8]; };
__global__ __launch_bounds__(256) void cvt_small(SmallCvt sc, const int* __restrict__ flag)
{
    bool isb = (*flag != 0);
    int stride = gridDim.x * 256;
    #pragma unroll
    for (int seg = 0; seg < 8; ++seg) {
        int n = sc.n[seg];
        for (int i = blockIdx.x * 256 + threadIdx.x; i < n; i += stride) {
            if (isb) ((ushort*)sc.d[seg])[i] = ((const ushort*)sc.s[seg])[i];
            else     sc.d[seg][i] = f2b(((const float*)sc.s[seg])[i]);
        }
    }
}

// ---------------- fused transpose(+cvt) of all 7 weights ---------------------
struct TDesc { const void* src; ushort* dst; int R, C, tile0; };
struct TAll { TDesc d[7]; };
__global__ __launch_bounds__(256) void transpose_all(
    TAll ta, const int* __restrict__ flag)
{
    bool isb = (*flag != 0);
    int bid = blockIdx.x;
    int seg = 0;
    #pragma unroll
    for (int i = 1; i < 7; ++i) if (bid >= ta.d[i].tile0) seg = i;
    const void* src = ta.d[seg].src;
    ushort* dst = ta.d[seg].dst;
    int R = ta.d[seg].R, C = ta.d[seg].C;
    int t = bid - ta.d[seg].tile0;
    int tilesX = C >> 5;
    int c0 = (t % tilesX) * 32, r0 = (t / tilesX) * 32;

    __shared__ ushort tile[32][33];
    int x = threadIdx.x, y = threadIdx.y;  // 32 x 8
    #pragma unroll
    for (int dy = 0; dy < 32; dy += 8) {
        size_t idx = (size_t)(r0 + y + dy) * C + c0 + x;
        ushort v;
        if (isb) v = ((const ushort*)src)[idx];
        else { bf16 tb = f2b(((const float*)src)[idx]); v = *(ushort*)&tb; }
        tile[y + dy][x] = v;
    }
    __syncthreads();
    #pragma unroll
    for (int dy = 0; dy < 32; dy += 8)
        dst[(size_t)(c0 + y + dy) * R + r0 + x] = tile[x][y + dy];
}

// ---------------- LayerNorm (+ optional fused gk low-rank MLP) ----------------
template <int DO_GK>
__global__ __launch_bounds__(256) void ln_kernel(
    const void* __restrict__ x, const bf16* __restrict__ w, const bf16* __restrict__ b,
    bf16* __restrict__ out, const int* __restrict__ flag, int force,
    const bf16* __restrict__ w1, const bf16* __restrict__ w2,
    const bf16* __restrict__ b2i, bf16* __restrict__ gkout)
{
    bool isb = (force >= 0) ? (force != 0) : (*flag != 0);
    size_t base = (size_t)blockIdx.x * HM;
    int tid = threadIdx.x;
    float v[4], s = 0.f, s2 = 0.f;
    #pragma unroll
    for (int u = 0; u < 4; ++u) {
        size_t idx = base + tid + u * 256;
        float f = isb ? b2f(((const bf16*)x)[idx]) : ((const float*)x)[idx];
        v[u] = f; s += f; s2 += f * f;
    }
    #pragma unroll
    for (int off = 32; off >= 1; off >>= 1) {
        s  += __shfl_down(s, off);
        s2 += __shfl_down(s2, off);
    }
    __shared__ float ra[4], rb[4];
    __shared__ float hrow[1024];
    int wave = tid >> 6;
    if ((tid & 63) == 0) { ra[wave] = s; rb[wave] = s2; }
    __syncthreads();
    s = ra[0] + ra[1] + ra[2] + ra[3];
    s2 = rb[0] + rb[1] + rb[2] + rb[3];
    float mean = s * (1.f / HM);
    float var = fmaxf(s2 * (1.f / HM) - mean * mean, 0.f);
    float rs = rsqrtf(var + 1e-5f);
    #pragma unroll
    for (int u = 0; u < 4; ++u) {
        int col = tid + u * 256;
        float h = (v[u] - mean) * rs * b2f(w[col]) + b2f(b[col]);
        out[base + col] = f2b(h);
        if constexpr (DO_GK) hrow[col] = h;
    }
    if constexpr (DO_GK) {
        __syncthreads();
        int d = tid & 15, seg = tid >> 4;
        float sg = 0.f;
        #pragma unroll 8
        for (int j = 0; j < 64; ++j) {
            int i = seg * 64 + j;
            sg += hrow[i] * b2f(w1[i * 16 + d]);
        }
        __shared__ float red[256];
        __shared__ float g1[16];
        red[tid] = sg;
        __syncthreads();
        if (tid < 16) {
            float t = 0.f;
            #pragma unroll
            for (int s2i = 0; s2i < 16; ++s2i) t += red[s2i * 16 + tid];
            g1[tid] = t;
        }
        __syncthreads();
        #pragma unroll
        for (int rep = 0; rep < 2; ++rep) {
            int n = tid + rep * 256;
            float z = b2f(b2i[n]);
            #pragma unroll
            for (int r = 0; r < 16; ++r) z += g1[r] * b2f(w2[r * 512 + n]);
            z = clampf(z, 30.f);
            float ls = (z >= 0.f) ? -log1pf(expf(-z)) : (z - log1pf(expf(z)));
            gkout[blockIdx.x * 512 + n] = f2b(ls * 0.0625f);
        }
    }
}

// ---------------- 8-phase MFMA GEMM, BM=256, BN=256|128, BK=64 ---------------
// 512 thr = 8 waves (2M x 4N); per-wave C = 128 x BN/4. 4 quadrant-phases per
// K-tile: q0=(mh0,nh0) q1=(mh0,nh1) q2=(mh1,nh1) q3=(mh1,nh0).
// Region deaths in tile t's buffer: A-mh0 after q1, B-nh1 after q2, rest q3.
// Stage issue (1 half-tile/phase): q0:(t+1).A1  q1:(t+1).B0  q2:(t+2).A0
// q3:(t+2).B1  -> at each tile boundary exactly A0+B1 of t+2 in flight
// => s_waitcnt vmcnt(4) (BN=128: 3), never 0 in steady state.
// LDS tiles row-major [rows][64] bf16, XOR swizzle slot^=(row&7): linear
// global_load_lds dest + pre-swizzled GLOBAL src + swizzled ds_read (both
// sides same involution). MODE: 0 plain bf16; 1 f32=resid(flag)+acc;
// 2 bf16=gelu(acc+bias); 3 resid_f32+acc+bias -> dtype per flag.
template <int BN, int MODE>
__global__ __launch_bounds__(512, 2) void gemm8p(
    const bf16* __restrict__ A, const bf16* __restrict__ Wt,
    const bf16* __restrict__ bias, const void* __restrict__ resid,
    void* __restrict__ out, int M, int N, int K, const int* __restrict__ oflag)
{
    constexpr int NFRAG  = BN / 128;           // B frags per phase (2 or 1)
    constexpr int BLOADS = (BN == 256) ? 2 : 1;  // gload_lds per thread / B-half

    extern __shared__ ushort sm[];
    ushort* smA = sm;                     // 2 bufs x [256][64]
    ushort* smB = sm + 32768;             // 2 bufs x [BN][64]

    int tid = threadIdx.x;
    int wid = tid >> 6, l = tid & 63;
    int wm = wid >> 2, wn = wid & 3;
    int r16 = l & 15, quad = l >> 4;
    int bm = blockIdx.x * 256, bn = blockIdx.y * BN;
    bool isb = false;
    if constexpr (MODE == 1 || MODE == 3) isb = (*oflag != 0);

    const ushort* Au = (const ushort*)A;
    const ushort* Wu = (const ushort*)Wt;
    const int NT = K >> 6;

    // stage A half h (rows with bit6==h) of K-tile t into buf t&1.
    auto stageA = [&](int t, int h) {
        #pragma unroll
        for (int i = 0; i < 2; ++i) {
            int j = i * 512 + tid;
            int lr = j >> 3, slot = j & 7;
            int r = (lr & 63) + h * 64 + (lr >> 6) * 128;
            int sl = slot ^ (r & 7);
            const ushort* g = Au + (size_t)(bm + r) * K + t * 64 + sl * 8;
            GLDS16(g, &smA[(t & 1) * 16384 + r * 64 + slot * 8]);
        }
    };
    // stage B half h (BN=256: bit5==h; BN=128: bit4==h) of K-tile t.
    auto stageB = [&](int t, int h) {
        #pragma unroll
        for (int i = 0; i < BLOADS; ++i) {
            int j = i * 512 + tid;
            int lr = j >> 3, slot = j & 7;
            int r = (BN == 256) ? ((lr & 31) + h * 32 + (lr >> 5) * 64)
                                : ((lr & 15) + h * 16 + (lr >> 4) * 32);
            int sl = slot ^ (r & 7);
            const ushort* g = Wu + (size_t)(bn + r) * K + t * 64 + sl * 8;
            GLDS16(g, &smB[(t & 1) * (BN * 64) + r * 64 + slot * 8]);
        }
    };

    // swizzled ds_read column offsets (ushorts): logical kh*32+quad*8, XOR row&7
    int colx0 = (quad * 8) ^ ((r16 & 7) * 8);
    int colx1 = colx0 ^ 32;

    f32x4 acc[8][BN / 64] = {};

    // prologue: tile0 complete + t1.A0,B1 issued; wait leaves those in flight.
    stageA(0, 0); stageB(0, 0); stageA(0, 1); stageB(0, 1);
    if (NT > 1) { stageA(1, 0); stageB(1, 1); }
    if constexpr (BN == 256) asm volatile("s_waitcnt vmcnt(4)" ::: "memory");
    else                     asm volatile("s_waitcnt vmcnt(3)" ::: "memory");
    __builtin_amdgcn_s_barrier();

    for (int t = 0; t < NT; ++t) {
        const int abase = (t & 1) * 16384;
        const int bbase = (t & 1) * (BN * 64);
        #pragma unroll
        for (int q = 0; q < 4; ++q) {
            const int mh = q >> 1;
            const int nh = (q == 1 || q == 2) ? 1 : 0;
            // ds-load this quadrant's fragments (swizzled)
            bf16x8 af[2][4], bw[2][NFRAG];
            #pragma unroll
            for (int mf = 0; mf < 4; ++mf) {
                int r = wm * 128 + mh * 64 + mf * 16 + r16;
                af[0][mf] = *(const bf16x8*)&smA[abase + r * 64 + colx0];
                af[1][mf] = *(const bf16x8*)&smA[abase + r * 64 + colx1];
            }
            #pragma unroll
            for (int nf = 0; nf < NFRAG; ++nf) {
                int r = wn * (BN / 4) + nh * (NFRAG * 16) + nf * 16 + r16;
                bw[0][nf] = *(const bf16x8*)&smB[bbase + r * 64 + colx0];
                bw[1][nf] = *(const bf16x8*)&smB[bbase + r * 64 + colx1];
            }
            // stage issue into regions dead since the previous phase
            if (q == 0) { if (t + 1 < NT) stageA(t + 1, 1); }
            if (q == 1) { if (t + 1 < NT) stageB(t + 1, 0); }
            if (q == 2) { if (t + 2 < NT) stageA(t + 2, 0); }
            if (q == 3) { if (t + 2 < NT) stageB(t + 2, 1); }
            __builtin_amdgcn_s_barrier();
            asm volatile("s_waitcnt lgkmcnt(0)" ::: "memory");
            __builtin_amdgcn_s_setprio(1);
            #pragma unroll
            for (int mf = 0; mf < 4; ++mf)
                #pragma unroll
                for (int nf = 0; nf < NFRAG; ++nf) {
                    f32x4& a = acc[mh * 4 + mf][nh * NFRAG + nf];
                    a = __builtin_amdgcn_mfma_f32_16x16x32_bf16(af[0][mf], bw[0][nf], a, 0, 0, 0);
                    a = __builtin_amdgcn_mfma_f32_16x16x32_bf16(af[1][mf], bw[1][nf], a, 0, 0, 0);
                }
            __builtin_amdgcn_s_setprio(0);
            if (q == 3) {
                if (t + 2 < NT) {
                    if constexpr (BN == 256) asm volatile("s_waitcnt vmcnt(4)" ::: "memory");
                    else                     asm volatile("s_waitcnt vmcnt(3)" ::: "memory");
                } else {
                    asm volatile("s_waitcnt vmcnt(0)" ::: "memory");
                }
            }
            __builtin_amdgcn_s_barrier();
        }
    }

    // epilogue
    #pragma unroll
    for (int am = 0; am < 8; ++am) {
        int row0 = bm + wm * 128 + am * 16 + quad * 4;
        #pragma unroll
        for (int an = 0; an < BN / 64; ++an) {
            int col = bn + wn * (BN / 4) + an * 16 + r16;
            #pragma unroll
            for (int r = 0; r < 4; ++r) {
                size_t idx = (size_t)(row0 + r) * N + col;
                float v = acc[am][an][r];
                if constexpr (MODE == 0) {
                    ((bf16*)out)[idx] = f2b(clampf(v, 1e4f));
                } else if constexpr (MODE == 2) {
                    float t = clampf(v + b2f(bias[col]), 50.f);
                    ((bf16*)out)[idx] = f2b(0.5f * t * (1.f + erff(t * 0.70710678f)));
                } else if constexpr (MODE == 1) {
                    float rv = isb ? b2f(((const bf16*)resid)[idx])
                                   : ((const float*)resid)[idx];
                    ((float*)out)[idx] = clampf(rv + v, 1e5f);
                } else {
                    float t = clampf(v + b2f(bias[col]) + ((const float*)resid)[idx], 2e5f);
                    if (isb) ((bf16*)out)[idx] = f2b(t);
                    else     ((float*)out)[idx] = t;
                }
            }
        }
    }
}

// ---------------- GLA phase 1 (parallel segmented scan) ----------------
__global__ __launch_bounds__(256) void gla_phase1(
    const bf16* __restrict__ gkb, const bf16* __restrict__ qvg,
    float* __restrict__ clbuf, float* __restrict__ Dbuf, float* __restrict__ Pbuf)
{
    int bh = blockIdx.x, c = blockIdx.y;
    int b = bh >> 4, hh = bh & 15;
    int row0 = b * 2048 + c * CHK;
    __shared__ float glog[CHK][DK + 1];
    __shared__ float wk[CHK][DK + 1];
    __shared__ float segsum[8][DK + 1];
    __shared__ __align__(16) ushort vt[CHK][DV];
    int tid = threadIdx.x;
    int k = tid & 31, i8 = (tid >> 5) * 8;
    int seg = tid >> 5;
    #pragma unroll
    for (int u = 0; u < 8; ++u) {
        int i = i8 + u;
        float g = b2f(gkb[(size_t)(row0 + i) * 512 + hh * 32 + k]);
        glog[i][k] = fminf(fmaxf(g, -2.f), 0.f);
    }
    {
        int cc = tid & 7, ii = tid >> 3;
        #pragma unroll
        for (int h = 0; h < 2; ++h) {
            int i = ii + h * 32;
            uint4 val = *(const uint4*)((const ushort*)qvg + (size_t)(row0 + i) * 3072 + 1024 + hh * 64 + cc * 8);
            *(uint4*)&vt[i][cc * 8] = val;
        }
    }
    __syncthreads();
    {
        float run = 0.f;
        #pragma unroll
        for (int u = 0; u < 8; ++u) {
            run += glog[i8 + u][k];
            glog[i8 + u][k] = run;
        }
        segsum[seg][k] = run;
    }
    __syncthreads();
    {
        float off = 0.f;
        for (int s = 0; s < seg; ++s) off += segsum[s][k];
        #pragma unroll
        for (int u = 0; u < 8; ++u) glog[i8 + u][k] += off;
    }
    __syncthreads();
    #pragma unroll
    for (int u = 0; u < 8; ++u) {
        int i = i8 + u;
        float cl = glog[i][k];
        float cl63 = glog[CHK - 1][k];
        clbuf[(size_t)(row0 + i) * 512 + hh * 32 + k] = cl;
        wk[i][k] = expf(fmaxf(cl63 - cl, -60.f)) *
            b2f(qvg[(size_t)(row0 + i) * 3072 + 512 + hh * 32 + k]);
    }
    if (tid < 32) Dbuf[(size_t)(bh * 32 + c) * 32 + tid] = expf(glog[CHK - 1][tid]);
    __syncthreads();
    int kk = tid >> 3, v8 = (tid & 7) * 8;
    float acc[8] = {};
    for (int j = 0; j < CHK; ++j) {
        float w = wk[j][kk];
        uint4 raw = *(const uint4*)&vt[j][v8];
        acc8(w, raw, acc);
    }
    float* Pp = Pbuf + (size_t)(bh * 32 + c) * 2048 + kk * 64 + v8;
    #pragma unroll
    for (int u = 0; u < 8; ++u) Pp[u] = acc[u];
}

// ---------------- GLA phase 2: scan ----------------
__global__ __launch_bounds__(256) void gla_scan(
    const float* __restrict__ Pbuf, const float* __restrict__ Dbuf,
    float* __restrict__ Sbuf)
{
    int bh = blockIdx.x >> 3, vg8 = blockIdx.x & 7;
    int kk = threadIdx.x >> 3, vv = vg8 * 8 + (threadIdx.x & 7);
    float S = 0.f;
    for (int c = 0; c < NC; ++c) {
        size_t idx = (size_t)(bh * 32 + c) * 2048 + kk * 64 + vv;
        float P = Pbuf[idx];
        float D = Dbuf[(size_t)(bh * 32 + c) * 32 + kk];
        Sbuf[idx] = S;
        S = D * S + P;
    }
}

// ---------------- GLA phase 3 ----------------
__global__ __launch_bounds__(256) void gla_phase3(
    const bf16* __restrict__ qvg,
    const float* __restrict__ clbuf, const float* __restrict__ Sbuf,
    const bf16* __restrict__ rmsw, bf16* __restrict__ obuf)
{
    int bh = blockIdx.x, c = blockIdx.y;
    int b = bh >> 4, hh = bh & 15;
    int row0 = b * 2048 + c * CHK;
    __shared__ float qs[CHK][36], ks[CHK][36];
    __shared__ float S0[DK][68];
    __shared__ float Amat[CHK][CHK + 1];
    __shared__ __align__(16) ushort vt[CHK][DV];
    int tid = threadIdx.x;
    {
        int k = tid & 31, i8 = (tid >> 5) * 8;
        #pragma unroll
        for (int u = 0; u < 8; ++u) {
            int i = i8 + u;
            size_t r = (size_t)(row0 + i);
            int col = hh * 32 + k;
            float cl = fmaxf(clbuf[r * 512 + col], -60.f);
            qs[i][k] = b2f(qvg[r * 3072 + col]) * expf(cl) * 0.17677669529663687f;
            ks[i][k] = b2f(qvg[r * 3072 + 512 + col]) * expf(-cl);
        }
    }
    {
        int cc = tid & 7, ii = tid >> 3;
        #pragma unroll
        for (int h = 0; h < 2; ++h) {
            int i = ii + h * 32;
            uint4 val = *(const uint4*)((const ushort*)qvg + (size_t)(row0 + i) * 3072 + 1024 + hh * 64 + cc * 8);
            *(uint4*)&vt[i][cc * 8] = val;
        }
    }
    {
        int kk = tid >> 3, v8 = (tid & 7) * 8;
        const float* Sp = Sbuf + (size_t)(bh * 32 + c) * 2048 + kk * 64 + v8;
        *(f32x4*)&S0[kk][v8]     = *(const f32x4*)Sp;
        *(f32x4*)&S0[kk][v8 + 4] = *(const f32x4*)(Sp + 4);
    }
    __syncthreads();
    int i = tid >> 2, jb = tid & 3;
    for (int jj = 0; jj < 16; ++jj) {
        int j = jb + jj * 4;
        float d = 0.f;
        if (j <= i) {
            const f32x4* qp = (const f32x4*)qs[i];
            const f32x4* kp = (const f32x4*)ks[j];
            #pragma unroll
            for (int q8 = 0; q8 < 8; ++q8) {
                f32x4 a = qp[q8], bq = kp[q8];
                d += a.x * bq.x + a.y * bq.y + a.z * bq.z + a.w * bq.w;
            }
        }
        Amat[i][j] = d;
    }
    __syncthreads();
    float o[16] = {};
    int vv = jb * 16;
    for (int j = 0; j < CHK; ++j) {
        float a = Amat[i][j];
        uint4 r0 = *(const uint4*)&vt[j][vv];
        uint4 r1 = *(const uint4*)&vt[j][vv + 8];
        acc8(a, r0, o);
        acc8(a, r1, o + 8);
    }
    #pragma unroll
    for (int kk = 0; kk < DK; ++kk) {
        float qv = qs[i][kk];
        const f32x4* Sp = (const f32x4*)&S0[kk][vv];
        #pragma unroll
        for (int q4 = 0; q4 < 4; ++q4) {
            f32x4 sv = Sp[q4];
            o[q4 * 4 + 0] += qv * sv.x; o[q4 * 4 + 1] += qv * sv.y;
            o[q4 * 4 + 2] += qv * sv.z; o[q4 * 4 + 3] += qv * sv.w;
        }
    }
    float ss = 0.f;
    #pragma unroll
    for (int u = 0; u < 16; ++u) ss += o[u] * o[u];
    ss += __shfl_xor(ss, 1);
    ss += __shfl_xor(ss, 2);
    float sc = rsqrtf(fmaxf(ss, 0.f) * (1.f / DV) + 1e-5f);
    size_t r = (size_t)(row0 + i);
    #pragma unroll
    for (int u = 0; u < 16; ++u) {
        float g = b2f(qvg[r * 3072 + 2048 + hh * 64 + vv + u]);
        float sw = g / (1.f + expf(-g));
        obuf[r * 1024 + hh * 64 + vv + u] = f2b(clampf(o[u] * sc * b2f(rmsw[vv + u]) * sw, 3e4f));
    }
}

// ---------------- launcher ----------------
extern "C" void kernel_launch(void* const* d_in, const int* in_sizes, int n_in,
                              void* d_out, int out_size, void* d_ws, size_t ws_size,
                              hipStream_t stream) {
    (void)in_sizes; (void)n_in; (void)out_size; (void)ws_size;

    char* ws = (char*)d_ws;
    const size_t MB = 1024 * 1024;
    const size_t KB = 1024;
    bf16*  WqkT = (bf16*)(ws + 0);
    bf16*  WkT  = (bf16*)(ws + 1 * MB);
    bf16*  WvgT = (bf16*)(ws + 2 * MB);
    bf16*  WgT  = (bf16*)(ws + 4 * MB);
    bf16*  WoT  = (bf16*)(ws + 6 * MB);
    bf16*  W1T  = (bf16*)(ws + 8 * MB);
    bf16*  W2T  = (bf16*)(ws + 12 * MB);
    bf16*  hbuf = (bf16*)(ws + 16 * MB);
    bf16*  qvg  = (bf16*)(ws + 24 * MB);
    bf16*  gkb  = (bf16*)(ws + 48 * MB);
    float* clbf = (float*)(ws + 52 * MB);
    float* Dbuf = (float*)(ws + 60 * MB);
    float* Pbuf = (float*)(ws + 61 * MB);
    float* Sbuf = (float*)(ws + 69 * MB);
    bf16*  obuf = (bf16*)(ws + 61 * MB);
    float* ybuf = (float*)(ws + 32 * MB);
    bf16*  f1   = (bf16*)(ws + 48 * MB);
    bf16*  clnw = (bf16*)(ws + 85 * MB);
    bf16*  clnb = (bf16*)(ws + 85 * MB + 64 * KB);
    bf16*  cgw1 = (bf16*)(ws + 85 * MB + 128 * KB);
    bf16*  cgw2 = (bf16*)(ws + 85 * MB + 192 * KB);
    bf16*  cgb2 = (bf16*)(ws + 85 * MB + 256 * KB);
    bf16*  crms = (bf16*)(ws + 85 * MB + 320 * KB);
    bf16*  cb1  = (bf16*)(ws + 85 * MB + 384 * KB);
    bf16*  cb2  = (bf16*)(ws + 85 * MB + 448 * KB);
    int*   flag = (int*)(ws + 85 * MB + 512 * KB);

    hipLaunchKernelGGL(detect_dtype, dim3(1), dim3(256), 0, stream,
                       (const unsigned int*)d_in[0], flag);

    SmallCvt sc;
    sc.s[0] = d_in[1];  sc.d[0] = clnw; sc.n[0] = 1024;
    sc.s[1] = d_in[2];  sc.d[1] = clnb; sc.n[1] = 1024;
    sc.s[2] = d_in[6];  sc.d[2] = cgw1; sc.n[2] = 16384;
    sc.s[3] = d_in[7];  sc.d[3] = cgw2; sc.n[3] = 8192;
    sc.s[4] = d_in[8];  sc.d[4] = cgb2; sc.n[4] = 512;
    sc.s[5] = d_in[10]; sc.d[5] = crms; sc.n[5] = 64;
    sc.s[6] = d_in[13]; sc.d[6] = cb1;  sc.n[6] = 2048;
    sc.s[7] = d_in[15]; sc.d[7] = cb2;  sc.n[7] = 1024;
    hipLaunchKernelGGL(cvt_small, dim3(64), dim3(256), 0, stream, sc, flag);

    TAll ta;
    ta.d[0] = { d_in[3],  (ushort*)WqkT, 1024, 512,  0 };
    ta.d[1] = { d_in[4],  (ushort*)WkT,  1024, 512,  512 };
    ta.d[2] = { d_in[5],  (ushort*)WvgT, 1024, 1024, 1024 };
    ta.d[3] = { d_in[9],  (ushort*)WgT,  1024, 1024, 2048 };
    ta.d[4] = { d_in[11], (ushort*)WoT,  1024, 1024, 3072 };
    ta.d[5] = { d_in[12], (ushort*)W1T,  1024, 2048, 4096 };
    ta.d[6] = { d_in[14], (ushort*)W2T,  2048, 1024, 6144 };
    hipLaunchKernelGGL(transpose_all, dim3(8192), dim3(32, 8), 0, stream, ta, flag);

    // LN1 + fused gk
    hipLaunchKernelGGL((ln_kernel<1>), dim3(BT), dim3(256), 0, stream,
                       d_in[0], clnw, clnb, hbuf, (const int*)flag, -1,
                       cgw1, cgw2, cgb2, gkb);

    // qvg = h @ [Wq|Wk|Wv|Wg]  (M=4096, N=3072, K=1024)
    hipLaunchKernelGGL((gemm8p<256, 0>), dim3(16, 12), dim3(512), 131072, stream,
                       hbuf, WqkT, (const bf16*)nullptr, nullptr, (void*)qvg,
                       BT, 3072, 1024, flag);

    hipLaunchKernelGGL(gla_phase1, dim3(32, 32), dim3(256), 0, stream, gkb, qvg, clbf, Dbuf, Pbuf);
    hipLaunchKernelGGL(gla_scan, dim3(256), dim3(256), 0, stream, Pbuf, Dbuf, Sbuf);
    hipLaunchKernelGGL(gla_phase3, dim3(32, 32), dim3(256), 0, stream, qvg, clbf, Sbuf, crms, obuf);

    // y = x + o @ Wo  (M=4096, N=1024, K=1024), f32 out
    hipLaunchKernelGGL((gemm8p<128, 1>), dim3(16, 8), dim3(512), 98304, stream,
                       obuf, WoT, (const bf16*)nullptr, (const void*)d_in[0], (void*)ybuf,
                       BT, 1024, 1024, flag);
    hipLaunchKernelGGL((ln_kernel<0>), dim3(BT), dim3(256), 0, stream,
                       (const void*)ybuf, clnw, clnb, hbuf, (const int*)flag, 0,
                       (const bf16*)nullptr, (const bf16*)nullptr, (const bf16*)nullptr, (bf16*)nullptr);
    // f1 = gelu(h2 @ W1 + b1)  (M=4096, N=2048, K=1024)
    hipLaunchKernelGGL((gemm8p<128, 2>), dim3(16, 16), dim3(512), 98304, stream,
                       hbuf, W1T, cb1, nullptr, (void*)f1, BT, 2048, 1024, flag);
    // out = y + f1 @ W2 + b2  (M=4096, N=1024, K=2048)
    hipLaunchKernelGGL((gemm8p<128, 3>), dim3(16, 8), dim3(512), 98304, stream,
                       f1, W2T, cb2, (const void*)ybuf, d_out, BT, 1024, 2048, flag);
}